// Round 4
// baseline (382.389 us; speedup 1.0000x reference)
//
#include <hip/hip_runtime.h>
#include <math.h>

#define HH   1024
#define TT   2048
#define BB   32
#define NC   32            // chunks along T  -> 32*32 = 1024 blocks (4 blocks/CU)
#define TC   (TT / NC)     // 64 timesteps per block
#define NWV  4             // waves per block
#define TPW  (TC / NWV)    // 16 timesteps per wave
#define NTH  (NWV * 64)    // 256 threads
#define KSL  16            // k-slices for compute_v partials
#define HS   4             // H-slices for combine kernel

// ---------------- kernel 0a: vpart[ks][h] = sum_{k in slice} W_v[k]*W_attn[k,H+h] ----
__global__ __launch_bounds__(256) void compute_v_part(
    const float* __restrict__ W_attn, const float* __restrict__ W_v,
    float* __restrict__ vpart)
{
    const int h  = blockIdx.x * 256 + threadIdx.x;   // blockIdx.x in [0,4)
    const int ks = blockIdx.y;                       // [0,KSL)
    const int k0 = ks * (HH / KSL);
    const float* col = W_attn + HH + h;
    float s = 0.f;
#pragma unroll 8
    for (int k = k0; k < k0 + HH / KSL; ++k)
        s = fmaf(W_v[k], col[(size_t)k * (2 * HH)], s);
    vpart[ks * HH + h] = s;
}

// ---------------- kernel 0b: v[h] = sum_ks vpart[ks][h] ----------------
__global__ __launch_bounds__(256) void compute_v_reduce(
    const float* __restrict__ vpart, float* __restrict__ v_out)
{
    const int h = blockIdx.x * 256 + threadIdx.x;
    float s = 0.f;
#pragma unroll
    for (int ks = 0; ks < KSL; ++ks) s += vpart[ks * HH + h];
    v_out[h] = s;
}

// ---------------- kernel 1: fused score + online softmax + weighted sum ----------
// Wave-private: each wave covers full H (lane owns 16 floats), handles TPW
// contiguous timesteps with zero barriers in the hot loop; one LDS merge at end.
// Online softmax uses a wave-uniform branch: rescale only when the max updates.
__global__ __launch_bounds__(NTH) void attn_pass_kernel(
    const float* __restrict__ enc, const float* __restrict__ v,
    float* __restrict__ ws_m, float* __restrict__ ws_l,
    float* __restrict__ ws_acc)
{
    const int c    = blockIdx.x;
    const int b    = blockIdx.y;
    const int tid  = threadIdx.x;
    const int lane = tid & 63;
    const int wave = tid >> 6;

    // lane's H ownership: float4 slots lane, lane+64, lane+128, lane+192
    float4 v4[4];
#pragma unroll
    for (int j = 0; j < 4; ++j)
        v4[j] = reinterpret_cast<const float4*>(v)[lane + 64 * j];

    const int t0 = c * TC + wave * TPW;
    const float4* enc4 = reinterpret_cast<const float4*>(enc)
                         + ((size_t)b * TT + t0) * (HH / 4);

    float  m = -INFINITY;
    float  l = 0.f;
    float4 acc[4] = {make_float4(0,0,0,0), make_float4(0,0,0,0),
                     make_float4(0,0,0,0), make_float4(0,0,0,0)};

    float4 e[4];
#pragma unroll
    for (int j = 0; j < 4; ++j) e[j] = enc4[lane + 64 * j];

    for (int i = 0; i < TPW; ++i) {
        float4 en[4];
        const bool more = (i + 1 < TPW);
        if (more) {
#pragma unroll
            for (int j = 0; j < 4; ++j)
                en[j] = enc4[(size_t)(i + 1) * (HH / 4) + lane + 64 * j];
        }
        // dot(enc_t, v) partial on this lane
        float p = 0.f;
#pragma unroll
        for (int j = 0; j < 4; ++j) {
            p = fmaf(e[j].x, v4[j].x, p);
            p = fmaf(e[j].y, v4[j].y, p);
            p = fmaf(e[j].z, v4[j].z, p);
            p = fmaf(e[j].w, v4[j].w, p);
        }
        // butterfly all-reduce: all lanes end with the bit-identical sum
#pragma unroll
        for (int off = 1; off < 64; off <<= 1)
            p += __shfl_xor(p, off, 64);

        if (p > m) {               // wave-uniform branch (p identical in all lanes)
            const float alpha = __expf(m - p);   // first iter: exp(-inf)=0
            l = fmaf(l, alpha, 1.f);
#pragma unroll
            for (int j = 0; j < 4; ++j) {
                acc[j].x = fmaf(acc[j].x, alpha, e[j].x);
                acc[j].y = fmaf(acc[j].y, alpha, e[j].y);
                acc[j].z = fmaf(acc[j].z, alpha, e[j].z);
                acc[j].w = fmaf(acc[j].w, alpha, e[j].w);
            }
            m = p;
        } else {                   // common path: no rescale
            const float w = __expf(p - m);
            l += w;
#pragma unroll
            for (int j = 0; j < 4; ++j) {
                acc[j].x = fmaf(w, e[j].x, acc[j].x);
                acc[j].y = fmaf(w, e[j].y, acc[j].y);
                acc[j].z = fmaf(w, e[j].z, acc[j].z);
                acc[j].w = fmaf(w, e[j].w, acc[j].w);
            }
        }
        if (more) {
#pragma unroll
            for (int j = 0; j < 4; ++j) e[j] = en[j];
        }
    }

    // ---- block-level merge of the 4 wave-private (m, l, acc) ----
    __shared__ float sm[NWV], sl[NWV];
    __shared__ float4 sacc[NWV * 256];   // 16 KB

    if (lane == 0) { sm[wave] = m; sl[wave] = l; }
    __syncthreads();

    float M = -INFINITY;
#pragma unroll
    for (int w2 = 0; w2 < NWV; ++w2) M = fmaxf(M, sm[w2]);
    const float myscale = __expf(m - M);

#pragma unroll
    for (int j = 0; j < 4; ++j) {
        float4 a = acc[j];
        a.x *= myscale; a.y *= myscale; a.z *= myscale; a.w *= myscale;
        sacc[wave * 256 + lane + 64 * j] = a;
    }
    __syncthreads();

    // thread tid reduces float4-slot `tid` across the 4 waves
    float4 r = make_float4(0, 0, 0, 0);
#pragma unroll
    for (int w2 = 0; w2 < NWV; ++w2) {
        const float4 a = sacc[w2 * 256 + tid];
        r.x += a.x; r.y += a.y; r.z += a.z; r.w += a.w;
    }

    const int idx = b * NC + c;
    reinterpret_cast<float4*>(ws_acc + (size_t)idx * HH)[tid] = r;
    if (tid == 0) {
        float L = 0.f;
#pragma unroll
        for (int w2 = 0; w2 < NWV; ++w2) L = fmaf(sl[w2], __expf(sm[w2] - M), L);
        ws_m[idx] = M;
        ws_l[idx] = L;
    }
}

// ---------------- kernel 2: combine chunk partials (H-sliced, 1 wave/block) -----
__global__ __launch_bounds__(64) void combine_kernel(
    const float* __restrict__ ws_m, const float* __restrict__ ws_l,
    const float* __restrict__ ws_acc, float* __restrict__ out)
{
    const int s    = blockIdx.x;    // H-slice [0,HS)
    const int b    = blockIdx.y;    // batch
    const int lane = threadIdx.x;   // 64 lanes, each owns one float4 of the slice

    float M = -INFINITY;
#pragma unroll
    for (int c = 0; c < NC; ++c) M = fmaxf(M, ws_m[b * NC + c]);

    float L = 0.f;
    float4 r = make_float4(0, 0, 0, 0);
#pragma unroll
    for (int c = 0; c < NC; ++c) {
        const float sc = __expf(ws_m[b * NC + c] - M);
        L = fmaf(sc, ws_l[b * NC + c], L);
        const float4 a = reinterpret_cast<const float4*>(
            ws_acc + (size_t)(b * NC + c) * HH)[s * 64 + lane];
        r.x = fmaf(sc, a.x, r.x);
        r.y = fmaf(sc, a.y, r.y);
        r.z = fmaf(sc, a.z, r.z);
        r.w = fmaf(sc, a.w, r.w);
    }
    const float inv = 1.f / L;
    reinterpret_cast<float4*>(out + (size_t)b * HH)[s * 64 + lane] =
        make_float4(r.x * inv, r.y * inv, r.z * inv, r.w * inv);
}

extern "C" void kernel_launch(void* const* d_in, const int* in_sizes, int n_in,
                              void* d_out, int out_size, void* d_ws, size_t ws_size,
                              hipStream_t stream) {
    // inputs: 0 encoder_outputs (B,T,H) f32 | 1 hidden | 2 W_attn (H,2H) f32
    //         3 b_attn | 4 W_v (1,H) f32 | 5 b_v
    // hidden / b_attn / b_v are constant in t -> cancel under softmax.
    const float* enc    = (const float*)d_in[0];
    const float* W_attn = (const float*)d_in[2];
    const float* W_v    = (const float*)d_in[4];
    float* out = (float*)d_out;

    float* ws     = (float*)d_ws;
    float* v      = ws;                          // 1024
    float* vpart  = ws + 1024;                   // 16*1024
    float* ws_m   = ws + 1024 + KSL * HH;        // 1024
    float* ws_l   = ws_m + BB * NC;              // 1024
    float* ws_acc = ws_l + BB * NC;              // 32*32*1024 = 4 MB

    compute_v_part<<<dim3(4, KSL), 256, 0, stream>>>(W_attn, W_v, vpart);
    compute_v_reduce<<<HH / 256, 256, 0, stream>>>(vpart, v);
    attn_pass_kernel<<<dim3(NC, BB), NTH, 0, stream>>>(enc, v, ws_m, ws_l, ws_acc);
    combine_kernel<<<dim3(HS, BB), 64, 0, stream>>>(ws_m, ws_l, ws_acc, out);
}